// Round 10
// baseline (2598.532 us; speedup 1.0000x reference)
//
#include <hip/hip_runtime.h>

// PathEncoder: B=8, N_NODE=512, N_TOK=8, N_PATHS=256, PATH_LEN=64, VOCAB=50000, H=256
// Round 10: base GRU split across 2 blocks per direction (4 base blocks), each
// owning 128 hidden cols -> 192KB weights = fully resident (REG 12 frags/wave +
// LDS 96KB), ZERO per-step weight streaming. Cross-block h-half exchange each
// step via device-scope atomics + release/acquire flag (parity double-buffer).
// Co-residency guaranteed: 132 blocks, 148.5KB LDS -> 1 block/CU. Path blocks
// (4..131) keep the r9 three-tier code + fused rank phase unchanged.
//
// ws layout (bytes): identical to round 9; pbuf/flags overlay dead wih_bt.
//   x       @ 0          4,194,304   [4096][256] f32
//   xbf     @ 4194304    2,097,152   [4096][256] bf16
//   xw3     @ 6291456   12,585,984   [4097]x1536 bf16 packed (r9 layout)
//   whhp    @ 18877440     786,432   packed whh bf16 B-frags (r9, path only)
//   wih_bt  @ 19663872     786,432   [1536][256] bf16 (dead after k_gemm_xw;
//                                    pbuf 32KB + flags 512B overlay here)
//   wr_bt   @ 20450304     524,288   [512][512] bf16 w_rank[:, :512]
//   rank_l  @ 20974592       2,048   [512] f32
//   bias2   @ 20976640       6,144   [1536] f32
//   keys    @ 20982784   8,404,992   [8][513][512] u32 scatter-max
//   base_v  @ 29387776   8,388,608   [8][512][512] f32
//   nx      @ 37776384 134,217,728   [131072][512] bf16

#define HH 256
#define NNODE 512
#define PLEN 64

typedef __attribute__((ext_vector_type(8))) short short8;
typedef __attribute__((ext_vector_type(4))) float f32x4;
typedef unsigned short ushort_t;
typedef __attribute__((address_space(1))) const void* gas_t;
typedef __attribute__((address_space(3))) void* las_t;

__device__ __forceinline__ f32x4 mfma16(short8 a, short8 b, f32x4 c) {
    return __builtin_amdgcn_mfma_f32_16x16x32_bf16(a, b, c, 0, 0, 0);
}
__device__ __forceinline__ ushort_t f2bf(float f) {
    unsigned u = __float_as_uint(f);
    u += 0x7fffu + ((u >> 16) & 1u);
    return (ushort_t)(u >> 16);
}
__device__ __forceinline__ float bf2f(ushort_t s) {
    return __uint_as_float(((unsigned)s) << 16);
}
__device__ __forceinline__ float sigm(float x) {
    return __builtin_amdgcn_rcpf(1.f + __expf(-x));
}
__device__ __forceinline__ float tanh_(float x) {
    return 1.f - 2.f * __builtin_amdgcn_rcpf(__expf(2.f * x) + 1.f);
}
__device__ __forceinline__ unsigned fkey(float f) {
    unsigned u = __float_as_uint(f);
    return (u & 0x80000000u) ? ~u : (u | 0x80000000u);
}
__device__ __forceinline__ float fdec(unsigned k) {
    unsigned u = (k & 0x80000000u) ? (k ^ 0x80000000u) : ~k;
    return __uint_as_float(u);
}

// xw3 remap (r9): col c in [0,1536) -> packed element offset within a row.
__device__ __forceinline__ int xw3_remap(int c) {
    const int dir = c >= 768;
    const int cd = c - dir * 768;
    const int g = cd >> 8, cc = cd & 255;
    const int w2 = cc >> 5, within = cc & 31;
    return dir * 768 + w2 * 96 + (within >> 1) * 6 + g * 2 + (within & 1);
}

// ---------------- embedding token max-pool ----------------
__global__ void k_embed(const int* __restrict__ nodes, const float* __restrict__ emb,
                        float* __restrict__ x, ushort_t* __restrict__ xbf)
{
    const int bn = blockIdx.x, h = threadIdx.x;
    const int* nd = nodes + bn * 8;
    float m = -3.4e38f;
#pragma unroll
    for (int k = 0; k < 8; ++k)
        m = fmaxf(m, emb[(size_t)nd[k] * HH + h]);
    x[(size_t)bn * HH + h] = m;
    xbf[(size_t)bn * HH + h] = f2bf(m);
}

// ---------------- pack weights (r9 layout, path whhp only) ----------------
__global__ void k_pack(const float* __restrict__ wf_ih, const float* __restrict__ wf_hh,
                       const float* __restrict__ bf_ih, const float* __restrict__ bf_hh,
                       const float* __restrict__ wb_ih, const float* __restrict__ wb_hh,
                       const float* __restrict__ bb_ih, const float* __restrict__ bb_hh,
                       const float* __restrict__ w_rank,
                       ushort_t* __restrict__ whhp, ushort_t* __restrict__ wih_bt,
                       ushort_t* __restrict__ wr_bt, float* __restrict__ rank_l,
                       float* __restrict__ bias2, ushort_t* __restrict__ xw3)
{
    int i = blockIdx.x * 256 + threadIdx.x;
    if (i < 393216) {
        // chunk c = (dir*8 + w)*48 + q; q -> (kt,g,n) per r9 three-tier order.
        const int e = i & 7, l = (i >> 3) & 63;
        const int c = i >> 9;
        const int q = c % 48;
        const int w2 = (c / 48) & 7;
        const int dir = c / 384;
        int kt, g;
        if (q < 12)      { kt = q / 6;            g = (q % 6) >> 1; }
        else if (q < 24) { kt = 2 + (q - 12) / 6; g = ((q - 12) % 6) >> 1; }
        else if (q < 28) { kt = 4;                g = (q - 24) >> 1; }
        else if (q < 30) { kt = 4;                g = 2; }
        else             { kt = 5 + (q - 30) / 6; g = ((q - 30) % 6) >> 1; }
        const int n = q & 1;
        const float* whh = dir ? wb_hh : wf_hh;
        whhp[i] = f2bf(whh[(g * 256 + w2 * 32 + 2 * (l & 15) + n) * 256 +
                           kt * 32 + (l >> 4) * 8 + e]);
        return;
    }
    i -= 393216;
    if (i < 393216) {   // wih_bt [1536][256]
        const int n = i >> 8, k = i & 255;
        const float* wih = (n < 768) ? wf_ih : wb_ih;
        wih_bt[i] = f2bf(wih[(n % 768) * 256 + k]);
        return;
    }
    i -= 393216;
    if (i < 262144) { wr_bt[i] = f2bf(w_rank[(i >> 9) * 513 + (i & 511)]); return; }
    i -= 262144;
    if (i < 512) { rank_l[i] = w_rank[i * 513 + 512]; return; }
    i -= 512;
    if (i < 1536) {
        const int c = i;
        const int dir = c >= 768;
        const int cd = c - dir * 768;
        const int g = cd >> 8;
        const float bi = dir ? bb_ih[cd] : bf_ih[cd];
        const float bh = (g < 2) ? (dir ? bb_hh[cd] : bf_hh[cd]) : 0.f;
        bias2[c] = bi + bh;
        xw3[(size_t)4096 * 1536 + xw3_remap(c)] = f2bf(bi + bh);  // padding row
    }
}

// ---------------- GEMM mainloop (256 thr, 128x128, BK=64) ----------------
template<int KD>
__device__ __forceinline__ void gemm_loop(const ushort_t* __restrict__ A,
                                          const ushort_t* __restrict__ Bt,
                                          ushort_t* al, ushort_t* bl,
                                          int bm, int bn, f32x4 acc[4][4])
{
    const int tid = threadIdx.x, w = tid >> 6, l = tid & 63;
    const int lm = l & 15, lh = l >> 4;
    const int wm = w >> 1, wn = w & 1;
    const int lr = l >> 3, lc = (l & 7) * 8;
    for (int k0 = 0; k0 < KD; k0 += 64) {
#pragma unroll
        for (int i = 0; i < 4; ++i) {
            const int c = w * 4 + i;
            const ushort_t* ga = A + (size_t)(bm + c * 8 + lr) * KD + k0 + lc;
            const ushort_t* gb = Bt + (size_t)(bn + c * 8 + lr) * KD + k0 + lc;
            __builtin_amdgcn_global_load_lds((gas_t)ga, (las_t)(al + c * 512), 16, 0, 0);
            __builtin_amdgcn_global_load_lds((gas_t)gb, (las_t)(bl + c * 512), 16, 0, 0);
        }
        __syncthreads();
#pragma unroll
        for (int kt = 0; kt < 2; ++kt) {
            short8 af[4], bfr[4];
            const int ko = kt * 32 + lh * 8;
#pragma unroll
            for (int m = 0; m < 4; ++m)
                af[m] = *(const short8*)(al + (wm * 64 + m * 16 + lm) * 64 + ko);
#pragma unroll
            for (int n = 0; n < 4; ++n)
                bfr[n] = *(const short8*)(bl + (wn * 64 + n * 16 + lm) * 64 + ko);
#pragma unroll
            for (int m = 0; m < 4; ++m)
#pragma unroll
                for (int n = 0; n < 4; ++n)
                    acc[m][n] = mfma16(af[m], bfr[n], acc[m][n]);
        }
        __syncthreads();
    }
}

// ---------------- xw GEMM: [4096][256] @ [256][1536] + bias2 -> packed bf16 ----------
__global__ void __launch_bounds__(256, 2)
k_gemm_xw(const ushort_t* __restrict__ xbf, const ushort_t* __restrict__ wih_bt,
          const float* __restrict__ bias2, ushort_t* __restrict__ xw3)
{
    __shared__ __align__(16) ushort_t al[128 * 64], bl[128 * 64];
    f32x4 acc[4][4] = {};
    const int bm = blockIdx.y * 128, bn = blockIdx.x * 128;
    gemm_loop<256>(xbf, wih_bt, al, bl, bm, bn, acc);
    const int tid = threadIdx.x, w = tid >> 6, l = tid & 63;
    const int lm = l & 15, lh = l >> 4, wm = w >> 1, wn = w & 1;
#pragma unroll
    for (int m = 0; m < 4; ++m)
#pragma unroll
        for (int rr = 0; rr < 4; ++rr) {
            const int row = bm + wm * 64 + m * 16 + lh * 4 + rr;
#pragma unroll
            for (int n = 0; n < 4; ++n) {
                const int col = bn + wn * 64 + n * 16 + lm;
                xw3[(size_t)row * 1536 + xw3_remap(col)] = f2bf(acc[m][n][rr] + bias2[col]);
            }
        }
}

// ---------------- base GRU: 2 blocks per dir, each owns 128 hidden cols ----------
// Weights fully resident: REG kt0-3 (12 frags pinned), LDS kt4-7 (96KB).
// Per-step h-half exchange with the partner block via device-scope atomics.
__device__ __forceinline__ void base_run(int dir, int half, int tid,
    const ushort_t* __restrict__ xw3, const float* __restrict__ whh,
    const float* __restrict__ bhh, ushort_t* __restrict__ wl,
    ushort_t (*hl)[4096], float* __restrict__ pbuf, unsigned* __restrict__ flags,
    float* __restrict__ base_v)
{
    const int w = tid >> 6, l = tid & 63;
    const int lm = l & 15, lh = l >> 4;
    const int hcol = half * 128 + w * 16 + lm;    // this lane's hidden col (col = l&15)
    const int kk = lh * 8;

    // REG tier: kt0..3 x 3 gates, direct f32->bf16 convert, pinned
    short8 Breg[12];
#pragma unroll
    for (int kt = 0; kt < 4; ++kt)
#pragma unroll
        for (int g = 0; g < 3; ++g) {
            const float* src = whh + (size_t)(g * 256 + hcol) * 256 + kt * 32 + kk;
            short8 v;
#pragma unroll
            for (int e = 0; e < 8; ++e) v[e] = (short)f2bf(src[e]);
            asm volatile("" : "+v"(v));
            Breg[kt * 3 + g] = v;
        }
    // LDS tier: kt4..7 x 3 gates -> wl[(fi*8+w)*512 + l*8]
#pragma unroll
    for (int kt = 4; kt < 8; ++kt)
#pragma unroll
        for (int g = 0; g < 3; ++g) {
            const float* src = whh + (size_t)(g * 256 + hcol) * 256 + kt * 32 + kk;
            short8 v;
#pragma unroll
            for (int e = 0; e < 8; ++e) v[e] = (short)f2bf(src[e]);
            *(short8*)(wl + ((size_t)(((kt - 4) * 3 + g) * 8 + w)) * 512 + l * 8) = v;
        }
    const float bn_ = bhh[512 + hcol];
    // xw3 packed offset for (g=0) at this lane's hidden col; g stride = 2 elements
    const int goff = dir * 768 + (hcol >> 5) * 96 + ((hcol & 31) >> 1) * 6 + (hcol & 1);

    unsigned* flag_own = flags + (dir * 2 + half) * 32;
    unsigned* flag_par = flags + (dir * 2 + (1 - half)) * 32;
    float* pb_own = pbuf + (dir * 2 + half) * 2048;
    const float* pb_par = pbuf + (dir * 2 + (1 - half)) * 2048;
    const int ph = 1 - half;

    __syncthreads();
    for (int i = tid; i < 4096; i += 512) hl[0][i] = 0;
    __syncthreads();

    int cur = 0;
    for (int step = 0; step < NNODE; ++step) {
        const int t = dir ? (NNODE - 1 - step) : step;
        // ---- receive partner h(step-1) into hl[cur] (rows 0..7, partner cols) ----
        if (step) {
            while (__hip_atomic_load(flag_par, __ATOMIC_ACQUIRE,
                                     __HIP_MEMORY_SCOPE_AGENT) < (unsigned)step) {}
            const float* src = pb_par + ((step - 1) & 1) * 1024;
#pragma unroll
            for (int i2 = 0; i2 < 2; ++i2) {
                const int i = tid * 2 + i2;
                const int row = i >> 7, c = i & 127;
                const float v = __hip_atomic_load(src + i, __ATOMIC_RELAXED,
                                                  __HIP_MEMORY_SCOPE_AGENT);
                const int col = ph * 128 + c;
                *(ushort_t*)((char*)hl[cur] + row * 512 +
                             ((col * 2) ^ ((row & 7) << 4))) = f2bf(v);
            }
        }
        __syncthreads();
        // xw gathers: 3 bf16 per (lane, ri)
        ushort_t gr[4], gz[4], gn[4];
#pragma unroll
        for (int ri = 0; ri < 4; ++ri) {
            const int sq = lh * 4 + ri;
            const int row = (sq < 8) ? ((sq << 9) + t) : 4096;
            const ushort_t* gp = xw3 + (size_t)row * 1536 + goff;
            gr[ri] = gp[0]; gz[ri] = gp[2]; gn[ri] = gp[4];
        }
        // gates = h @ whh^T for own 128 cols: 24 MFMA/wave, K=256
        f32x4 acc[3] = {};
        const char* hb = (const char*)hl[cur];
#pragma unroll
        for (int kt = 0; kt < 4; ++kt) {
            const short8 a = *(const short8*)(hb + lm * 512 +
                ((kt * 64 + lh * 16) ^ ((lm & 7) << 4)));
            acc[0] = mfma16(a, Breg[kt * 3 + 0], acc[0]);
            acc[1] = mfma16(a, Breg[kt * 3 + 1], acc[1]);
            acc[2] = mfma16(a, Breg[kt * 3 + 2], acc[2]);
        }
#pragma unroll
        for (int kt = 4; kt < 8; ++kt) {
            const short8 a = *(const short8*)(hb + lm * 512 +
                ((kt * 64 + lh * 16) ^ ((lm & 7) << 4)));
            const int fb = (kt - 4) * 3;
            acc[0] = mfma16(a, *(const short8*)(wl + ((size_t)((fb + 0) * 8 + w)) * 512 + l * 8), acc[0]);
            acc[1] = mfma16(a, *(const short8*)(wl + ((size_t)((fb + 1) * 8 + w)) * 512 + l * 8), acc[1]);
            acc[2] = mfma16(a, *(const short8*)(wl + ((size_t)((fb + 2) * 8 + w)) * 512 + l * 8), acc[2]);
        }
        // gates + h update for own cols
        ushort_t* hn_ = hl[cur ^ 1];
        float* pw = pb_own + (step & 1) * 1024;
#pragma unroll
        for (int ri = 0; ri < 4; ++ri) {
            const int sq = lh * 4 + ri;
            const int hoff = sq * 512 + ((hcol * 2) ^ ((sq & 7) << 4));
            const float hov = bf2f(*(const ushort_t*)(hb + hoff));
            const float rr = sigm(acc[0][ri] + bf2f(gr[ri]));
            const float zz = sigm(acc[1][ri] + bf2f(gz[ri]));
            const float nn = tanh_(bf2f(gn[ri]) + rr * (acc[2][ri] + bn_));
            const float h = (1.f - zz) * nn + zz * hov;
            *(ushort_t*)((char*)hn_ + hoff) = f2bf(h);
            if (sq < 8) {
                __hip_atomic_store(pw + sq * 128 + (hcol & 127), h,
                                   __ATOMIC_RELAXED, __HIP_MEMORY_SCOPE_AGENT);
                base_v[((size_t)(sq * NNODE + t)) * 512 + dir * 256 + hcol] = h;
            }
        }
        __syncthreads();   // drains vmcnt for all waves -> pbuf stores at coherence point
        if (tid == 0)
            __hip_atomic_store(flag_own, (unsigned)(step + 1),
                               __ATOMIC_RELEASE, __HIP_MEMORY_SCOPE_AGENT);
        cur ^= 1;
    }
}

// ---------------- path GRU scan (r9 three-tier, unchanged) ----------------
__device__ __forceinline__ void path_run(int dir, int sg, int tid,
    const ushort_t* __restrict__ xw3, const ushort_t* __restrict__ whhp,
    const float* __restrict__ bhh, ushort_t* __restrict__ wl,
    ushort_t (*hl)[4096], const int* idr, ushort_t* __restrict__ nx)
{
    const int w = tid >> 6, l = tid & 63;
    const int lm = l & 15, lh = l >> 4;
    const ushort_t* wp = whhp + ((size_t)(dir * 8 + w) * 48) * 512 + l * 8;

    short8 Breg[12];
#pragma unroll
    for (int q = 0; q < 12; ++q) {
        short8 v = *(const short8*)(wp + q * 512);
        asm volatile("" : "+v"(v));
        Breg[q] = v;
    }
#pragma unroll
    for (int q = 12; q < 28; ++q)
        __builtin_amdgcn_global_load_lds((gas_t)(wp + q * 512),
            (las_t)(wl + ((q - 12) * 8 + w) * 512), 16, 0, 0);

    const float bn0 = bhh[512 + w * 32 + lm * 2];
    const float bn1 = bhh[512 + w * 32 + lm * 2 + 1];

    __syncthreads();
    for (int i = tid; i < 4096; i += 512) hl[0][i] = 0;
    __syncthreads();

    int cur = 0;
    for (int step = 0; step < PLEN; ++step) {
        const int t = dir ? (PLEN - 1 - step) : step;
        uint3 gv[4];
#pragma unroll
        for (int ri = 0; ri < 4; ++ri) {
            const int sq = lh * 4 + ri;
            const int row = idr[(sq << 6) + t];
            gv[ri] = *(const uint3*)((const char*)xw3 +
                (size_t)row * 3072 + dir * 1536 + w * 192 + lm * 12);
        }
        short8 st[8];
#pragma unroll
        for (int j = 0; j < 8; ++j) st[j] = *(const short8*)(wp + (28 + j) * 512);

        f32x4 acc[3][2] = {};
        const char* hb = (const char*)hl[cur];
        short8 af;
#pragma unroll
        for (int kt = 0; kt < 2; ++kt) {
            af = *(const short8*)(hb + lm * 512 + ((kt * 64 + lh * 16) ^ ((lm & 7) << 4)));
#pragma unroll
            for (int j = 0; j < 6; ++j)
                acc[j >> 1][j & 1] = mfma16(af, Breg[kt * 6 + j], acc[j >> 1][j & 1]);
        }
#pragma unroll
        for (int kt = 2; kt < 4; ++kt) {
            af = *(const short8*)(hb + lm * 512 + ((kt * 64 + lh * 16) ^ ((lm & 7) << 4)));
            const int fb = (kt - 2) * 6;
#pragma unroll
            for (int j = 0; j < 6; ++j) {
                const short8 b = *(const short8*)(wl + ((fb + j) * 8 + w) * 512 + l * 8);
                acc[j >> 1][j & 1] = mfma16(af, b, acc[j >> 1][j & 1]);
            }
        }
        af = *(const short8*)(hb + lm * 512 + ((4 * 64 + lh * 16) ^ ((lm & 7) << 4)));
#pragma unroll
        for (int j = 0; j < 4; ++j) {
            const short8 b = *(const short8*)(wl + ((12 + j) * 8 + w) * 512 + l * 8);
            acc[j >> 1][j & 1] = mfma16(af, b, acc[j >> 1][j & 1]);
        }
        acc[2][0] = mfma16(af, st[0], acc[2][0]);
        acc[2][1] = mfma16(af, st[1], acc[2][1]);
        af = *(const short8*)(hb + lm * 512 + ((5 * 64 + lh * 16) ^ ((lm & 7) << 4)));
#pragma unroll
        for (int j = 0; j < 6; ++j)
            acc[j >> 1][j & 1] = mfma16(af, st[2 + j], acc[j >> 1][j & 1]);
#pragma unroll
        for (int j = 0; j < 6; ++j) st[2 + j] = *(const short8*)(wp + (36 + j) * 512);
        af = *(const short8*)(hb + lm * 512 + ((6 * 64 + lh * 16) ^ ((lm & 7) << 4)));
#pragma unroll
        for (int j = 0; j < 6; ++j)
            acc[j >> 1][j & 1] = mfma16(af, st[2 + j], acc[j >> 1][j & 1]);
#pragma unroll
        for (int j = 0; j < 6; ++j) st[2 + j] = *(const short8*)(wp + (42 + j) * 512);
        af = *(const short8*)(hb + lm * 512 + ((7 * 64 + lh * 16) ^ ((lm & 7) << 4)));
#pragma unroll
        for (int j = 0; j < 6; ++j)
            acc[j >> 1][j & 1] = mfma16(af, st[2 + j], acc[j >> 1][j & 1]);

        ushort_t* hn_ = hl[cur ^ 1];
#pragma unroll
        for (int ri = 0; ri < 4; ++ri) {
            const int sq = lh * 4 + ri;
            const unsigned hv = *(const unsigned*)(hb + sq * 512 +
                ((w * 64 + lm * 4) ^ ((sq & 7) << 4)));
            unsigned hpack = 0;
#pragma unroll
            for (int n = 0; n < 2; ++n) {
                const float xr = bf2f((ushort_t)(n ? (gv[ri].x >> 16) : (gv[ri].x & 0xffffu)));
                const float xz = bf2f((ushort_t)(n ? (gv[ri].y >> 16) : (gv[ri].y & 0xffffu)));
                const float xn = bf2f((ushort_t)(n ? (gv[ri].z >> 16) : (gv[ri].z & 0xffffu)));
                const float hov = bf2f((ushort_t)(n ? (hv >> 16) : (hv & 0xffffu)));
                const float rr = sigm(acc[0][n][ri] + xr);
                const float zz = sigm(acc[1][n][ri] + xz);
                const float nn = tanh_(xn + rr * (acc[2][n][ri] + (n ? bn1 : bn0)));
                const float h = (1.f - zz) * nn + zz * hov;
                hpack |= ((unsigned)f2bf(h)) << (n * 16);
            }
            *(unsigned*)((char*)hn_ + sq * 512 + ((w * 64 + lm * 4) ^ ((sq & 7) << 4))) = hpack;
            *(unsigned*)((char*)nx + (((size_t)((sg * 16 + sq) * PLEN + t)) * 512 +
                dir * 256 + w * 32 + lm * 2) * 2) = hpack;
        }
        __syncthreads();
        cur ^= 1;
    }
}

// ---------------- fused: blocks 0-3 = base halves; 4..131 = path + rank ----------
__global__ void __launch_bounds__(512)
k_scan(const int* __restrict__ paths, const ushort_t* __restrict__ xw3,
       const ushort_t* __restrict__ whhp,
       const float* __restrict__ wf_hh, const float* __restrict__ wb_hh,
       const float* __restrict__ bf_hh, const float* __restrict__ bb_hh,
       const ushort_t* __restrict__ wr_bt, const float* __restrict__ b_rank,
       const float* __restrict__ rank_l,
       ushort_t* __restrict__ nx, float* __restrict__ base_v,
       unsigned* __restrict__ keys, float* __restrict__ pbuf,
       unsigned* __restrict__ flags)
{
    __shared__ __align__(16) ushort_t wl[65536];    // 128KB
    __shared__ __align__(16) ushort_t hl[2][4096];  // 16KB
    __shared__ int idr[1024];                       // 4KB -> 148.5KB (1 block/CU)
    const int tid = threadIdx.x;
    const int w = tid >> 6, l = tid & 63;
    const int lm = l & 15, lh = l >> 4;

    if (blockIdx.x < 4) {
        const int dir = blockIdx.x >> 1, half = blockIdx.x & 1;
        base_run(dir, half, tid, xw3, dir ? wb_hh : wf_hh, dir ? bb_hh : bf_hh,
                 wl, hl, pbuf, flags, base_v);
        return;
    }
    const int sg = (int)blockIdx.x - 4;
    for (int i = tid; i < 1024; i += 512) {
        const int s = sg * 16 + (i >> 6), t = i & 63;
        const int id = paths[(s << 6) + t];
        idr[i] = (id < NNODE) ? (((s >> 8) << 9) + id) : 4096;
    }
    path_run(0, sg, tid, xw3, whhp, bf_hh, wl, hl, idr, nx);
    path_run(1, sg, tid, xw3, whhp, bb_hh, wl, hl, idr, nx);

    // ---- rank phase: own 1024 nx rows @ wr^T, 32 jobs of 128x128 tiles, K=512 ----
    __threadfence_block();
    __syncthreads();
    ushort_t* al = wl;
    ushort_t* bl = wl + 8192;
    const int wm = w >> 2, wn = w & 3;   // wave tile 64x32
#pragma unroll 1
    for (int job = 0; job < 32; ++job) {
        const int mt = job >> 2, ntile = job & 3;
        const size_t ar0 = (size_t)sg * 1024 + mt * 128;
        const int n0 = ntile * 128;
        f32x4 racc[4][2] = {};
        for (int k0 = 0; k0 < 512; k0 += 64) {
#pragma unroll
            for (int i = 0; i < 2; ++i) {
                const int c = w * 128 + i * 64 + l;
                const int row = c >> 3, j = c & 7;
                const int jp = j ^ (row & 7);
                __builtin_amdgcn_global_load_lds(
                    (gas_t)(nx + (ar0 + row) * 512 + k0 + jp * 8),
                    (las_t)(al + c * 8), 16, 0, 0);
                __builtin_amdgcn_global_load_lds(
                    (gas_t)(wr_bt + (size_t)(n0 + row) * 512 + k0 + jp * 8),
                    (las_t)(bl + c * 8), 16, 0, 0);
            }
            __syncthreads();
#pragma unroll
            for (int kt = 0; kt < 2; ++kt) {
                short8 av[4], bv[2];
#pragma unroll
                for (int m = 0; m < 4; ++m) {
                    const int r = wm * 64 + m * 16 + lm;
                    av[m] = *(const short8*)((const char*)al + r * 128 +
                            ((kt * 64 + lh * 16) ^ ((r & 7) << 4)));
                }
#pragma unroll
                for (int n = 0; n < 2; ++n) {
                    const int r = wn * 32 + n * 16 + lm;
                    bv[n] = *(const short8*)((const char*)bl + r * 128 +
                            ((kt * 64 + lh * 16) ^ ((r & 7) << 4)));
                }
#pragma unroll
                for (int m = 0; m < 4; ++m)
#pragma unroll
                    for (int n = 0; n < 2; ++n)
                        racc[m][n] = mfma16(av[m], bv[n], racc[m][n]);
            }
            __syncthreads();
        }
#pragma unroll
        for (int m = 0; m < 4; ++m)
#pragma unroll
            for (int rr = 0; rr < 4; ++rr) {
                const size_t grow = ar0 + wm * 64 + m * 16 + lh * 4 + rr;
                const int id = paths[grow];
                const float rv = __builtin_amdgcn_rcpf((float)(((grow >> 6) & 255) + 1));
                unsigned* kp = keys + (((grow >> 14) * 513 + id) << 9);
#pragma unroll
                for (int n = 0; n < 2; ++n) {
                    const int col = n0 + wn * 32 + n * 16 + lm;
                    const float v = racc[m][n][rr] + b_rank[col] + rank_l[col] * rv;
                    if (id < NNODE) {
                        const unsigned key = fkey(v);
                        if (key > kp[col]) atomicMax(kp + col, key);
                    }
                }
            }
    }
}

// ---------------- merge: v = has ? vmax : transit(x);  all_v = base_v + v ----------------
__global__ void k_merge(const unsigned* __restrict__ keys, const float* __restrict__ base_v,
                        const float* __restrict__ x, const float* __restrict__ w_transit,
                        const float* __restrict__ b_transit, float* __restrict__ out0)
{
    const int blk = blockIdx.x;
    const int b = blk >> 9, n = blk & 511;
    const int tid = threadIdx.x;
#pragma unroll
    for (int h = 0; h < 2; ++h) {
        const int o = tid + h * 256;
        const unsigned k = keys[((size_t)(b * 513 + n)) * 512 + o];
        float v;
        if (k) {
            v = fdec(k);
        } else {
            float a = b_transit[o];
            const float* wt = w_transit + o * HH;
            const float* xr = x + ((size_t)(b * NNODE + n)) * HH;
            for (int i = 0; i < HH; ++i) a += xr[i] * wt[i];
            v = a;
        }
        const size_t oi = ((size_t)(b * NNODE + n)) * 512 + o;
        out0[oi] = base_v[oi] + v;
    }
}

// ---------------- last_state: rowmax over nodes, then @ w_h.T + b_h ----------------
__global__ void k_last(const float* __restrict__ out0, const float* __restrict__ w_h,
                       const float* __restrict__ b_h, float* __restrict__ out1)
{
    __shared__ float m[512];
    const int b = blockIdx.x, tid = threadIdx.x;
#pragma unroll
    for (int h = 0; h < 2; ++h) {
        const int o = tid + h * 256;
        float mm = -3.4e38f;
        for (int n = 0; n < NNODE; ++n)
            mm = fmaxf(mm, out0[((size_t)(b * NNODE + n)) * 512 + o]);
        m[o] = mm;
    }
    __syncthreads();
    float a = b_h[tid];
    const float* wr = w_h + tid * 512;
    for (int j = 0; j < 512; ++j) a += m[j] * wr[j];
    out1[b * HH + tid] = a;
}

extern "C" void kernel_launch(void* const* d_in, const int* in_sizes, int n_in,
                              void* d_out, int out_size, void* d_ws, size_t ws_size,
                              hipStream_t stream)
{
    (void)in_sizes; (void)n_in; (void)out_size; (void)ws_size;
    const int* nodes = (const int*)d_in[0];
    const int* paths = (const int*)d_in[1];
    const float* emb = (const float*)d_in[2];
    const float* wf_ih = (const float*)d_in[3];
    const float* wf_hh = (const float*)d_in[4];
    const float* bf_ih = (const float*)d_in[5];
    const float* bf_hh = (const float*)d_in[6];
    const float* wb_ih = (const float*)d_in[7];
    const float* wb_hh = (const float*)d_in[8];
    const float* bb_ih = (const float*)d_in[9];
    const float* bb_hh = (const float*)d_in[10];
    const float* w_transit = (const float*)d_in[11];
    const float* b_transit = (const float*)d_in[12];
    const float* w_rank = (const float*)d_in[13];
    const float* b_rank = (const float*)d_in[14];
    const float* w_h = (const float*)d_in[15];
    const float* b_h = (const float*)d_in[16];

    char* ws = (char*)d_ws;
    float* x = (float*)(ws);
    ushort_t* xbf = (ushort_t*)(ws + 4194304);
    ushort_t* xw3 = (ushort_t*)(ws + 6291456);
    ushort_t* whhp = (ushort_t*)(ws + 18877440);
    ushort_t* wih_bt = (ushort_t*)(ws + 19663872);
    float* pbuf = (float*)(ws + 19663872);          // overlays wih_bt (dead after k_gemm_xw)
    unsigned* flags = (unsigned*)(ws + 19663872 + 32768);
    ushort_t* wr_bt = (ushort_t*)(ws + 20450304);
    float* rank_l = (float*)(ws + 20974592);
    float* bias2 = (float*)(ws + 20976640);
    unsigned* keys = (unsigned*)(ws + 20982784);
    float* base_v = (float*)(ws + 29387776);
    ushort_t* nx = (ushort_t*)(ws + 37776384);

    float* out0 = (float*)d_out;
    float* out1 = out0 + 2097152;

    hipMemsetAsync(keys, 0, 8404992, stream);
    k_embed<<<4096, 256, 0, stream>>>(nodes, emb, x, xbf);
    k_pack<<<4104, 256, 0, stream>>>(wf_ih, wf_hh, bf_ih, bf_hh, wb_ih, wb_hh,
                                     bb_ih, bb_hh, w_rank,
                                     whhp, wih_bt, wr_bt, rank_l, bias2, xw3);
    k_gemm_xw<<<dim3(12, 32), 256, 0, stream>>>(xbf, wih_bt, bias2, xw3);
    hipMemsetAsync(pbuf, 0, 33280, stream);         // zero pbuf + flags (wih_bt now dead)
    k_scan<<<132, 512, 0, stream>>>(paths, xw3, whhp, wf_hh, wb_hh, bf_hh, bb_hh,
                                    wr_bt, b_rank, rank_l, nx, base_v, keys,
                                    pbuf, flags);
    k_merge<<<4096, 256, 0, stream>>>(keys, base_v, x, w_transit, b_transit, out0);
    k_last<<<8, 256, 0, stream>>>(out0, w_h, b_h, out1);
}

// Round 11
// 1855.292 us; speedup vs baseline: 1.4006x; 1.4006x over previous
//
#include <hip/hip_runtime.h>

// PathEncoder: B=8, N_NODE=512, N_TOK=8, N_PATHS=256, PATH_LEN=64, VOCAB=50000, H=256
// Round 11: r9 three-tier + software-pipelined stream tier. The 20 streamed
// weight frags are h-independent, so they are issued ahead: b0/b1 prefetched
// during the PREVIOUS step's gates phase (2 chains stA/stB, 4 frags each);
// b2/b3/b4 reissued right after their chain's previous batch is consumed.
// sched_barrier(0) pins stop the register-pressure scheduler from sinking
// issues to their uses (r9's hidden failure: full L2 latency per batch).
//
// ws layout (bytes): identical to round 9.
//   x       @ 0          4,194,304   [4096][256] f32
//   xbf     @ 4194304    2,097,152   [4096][256] bf16
//   xw3     @ 6291456   12,585,984   [4097]x1536 bf16 packed (r9 layout)
//   whhp    @ 18877440     786,432   packed whh bf16 B-frags, chunk (dir*8+w)*48+q
//   wih_bt  @ 19663872     786,432   [1536][256] bf16 concat(wf_ih, wb_ih)
//   wr_bt   @ 20450304     524,288   [512][512] bf16 w_rank[:, :512]
//   rank_l  @ 20974592       2,048   [512] f32
//   bias2   @ 20976640       6,144   [1536] f32
//   keys    @ 20982784   8,404,992   [8][513][512] u32 scatter-max
//   base_v  @ 29387776   8,388,608   [8][512][512] f32
//   nx      @ 37776384 134,217,728   [131072][512] bf16

#define HH 256
#define NNODE 512
#define PLEN 64

typedef __attribute__((ext_vector_type(8))) short short8;
typedef __attribute__((ext_vector_type(4))) float f32x4;
typedef unsigned short ushort_t;
typedef __attribute__((address_space(1))) const void* gas_t;
typedef __attribute__((address_space(3))) void* las_t;

__device__ __forceinline__ f32x4 mfma16(short8 a, short8 b, f32x4 c) {
    return __builtin_amdgcn_mfma_f32_16x16x32_bf16(a, b, c, 0, 0, 0);
}
__device__ __forceinline__ ushort_t f2bf(float f) {
    unsigned u = __float_as_uint(f);
    u += 0x7fffu + ((u >> 16) & 1u);
    return (ushort_t)(u >> 16);
}
__device__ __forceinline__ float bf2f(ushort_t s) {
    return __uint_as_float(((unsigned)s) << 16);
}
__device__ __forceinline__ float sigm(float x) {
    return __builtin_amdgcn_rcpf(1.f + __expf(-x));
}
__device__ __forceinline__ float tanh_(float x) {
    return 1.f - 2.f * __builtin_amdgcn_rcpf(__expf(2.f * x) + 1.f);
}
__device__ __forceinline__ unsigned fkey(float f) {
    unsigned u = __float_as_uint(f);
    return (u & 0x80000000u) ? ~u : (u | 0x80000000u);
}
__device__ __forceinline__ float fdec(unsigned k) {
    unsigned u = (k & 0x80000000u) ? (k ^ 0x80000000u) : ~k;
    return __uint_as_float(u);
}

// xw3 remap (r9): col c in [0,1536) -> packed element offset within a row.
__device__ __forceinline__ int xw3_remap(int c) {
    const int dir = c >= 768;
    const int cd = c - dir * 768;
    const int g = cd >> 8, cc = cd & 255;
    const int w2 = cc >> 5, within = cc & 31;
    return dir * 768 + w2 * 96 + (within >> 1) * 6 + g * 2 + (within & 1);
}

// ---------------- embedding token max-pool ----------------
__global__ void k_embed(const int* __restrict__ nodes, const float* __restrict__ emb,
                        float* __restrict__ x, ushort_t* __restrict__ xbf)
{
    const int bn = blockIdx.x, h = threadIdx.x;
    const int* nd = nodes + bn * 8;
    float m = -3.4e38f;
#pragma unroll
    for (int k = 0; k < 8; ++k)
        m = fmaxf(m, emb[(size_t)nd[k] * HH + h]);
    x[(size_t)bn * HH + h] = m;
    xbf[(size_t)bn * HH + h] = f2bf(m);
}

// ---------------- pack weights (identical to r9) ----------------
__global__ void k_pack(const float* __restrict__ wf_ih, const float* __restrict__ wf_hh,
                       const float* __restrict__ bf_ih, const float* __restrict__ bf_hh,
                       const float* __restrict__ wb_ih, const float* __restrict__ wb_hh,
                       const float* __restrict__ bb_ih, const float* __restrict__ bb_hh,
                       const float* __restrict__ w_rank,
                       ushort_t* __restrict__ whhp, ushort_t* __restrict__ wih_bt,
                       ushort_t* __restrict__ wr_bt, float* __restrict__ rank_l,
                       float* __restrict__ bias2, ushort_t* __restrict__ xw3)
{
    int i = blockIdx.x * 256 + threadIdx.x;
    if (i < 393216) {
        const int e = i & 7, l = (i >> 3) & 63;
        const int c = i >> 9;
        const int q = c % 48;
        const int w2 = (c / 48) & 7;
        const int dir = c / 384;
        int kt, g;
        if (q < 12)      { kt = q / 6;            g = (q % 6) >> 1; }
        else if (q < 24) { kt = 2 + (q - 12) / 6; g = ((q - 12) % 6) >> 1; }
        else if (q < 28) { kt = 4;                g = (q - 24) >> 1; }
        else if (q < 30) { kt = 4;                g = 2; }
        else             { kt = 5 + (q - 30) / 6; g = ((q - 30) % 6) >> 1; }
        const int n = q & 1;
        const float* whh = dir ? wb_hh : wf_hh;
        whhp[i] = f2bf(whh[(g * 256 + w2 * 32 + 2 * (l & 15) + n) * 256 +
                           kt * 32 + (l >> 4) * 8 + e]);
        return;
    }
    i -= 393216;
    if (i < 393216) {   // wih_bt [1536][256]
        const int n = i >> 8, k = i & 255;
        const float* wih = (n < 768) ? wf_ih : wb_ih;
        wih_bt[i] = f2bf(wih[(n % 768) * 256 + k]);
        return;
    }
    i -= 393216;
    if (i < 262144) { wr_bt[i] = f2bf(w_rank[(i >> 9) * 513 + (i & 511)]); return; }
    i -= 262144;
    if (i < 512) { rank_l[i] = w_rank[i * 513 + 512]; return; }
    i -= 512;
    if (i < 1536) {
        const int c = i;
        const int dir = c >= 768;
        const int cd = c - dir * 768;
        const int g = cd >> 8;
        const float bi = dir ? bb_ih[cd] : bf_ih[cd];
        const float bh = (g < 2) ? (dir ? bb_hh[cd] : bf_hh[cd]) : 0.f;
        bias2[c] = bi + bh;
        xw3[(size_t)4096 * 1536 + xw3_remap(c)] = f2bf(bi + bh);  // padding row
    }
}

// ---------------- GEMM mainloop (256 thr, 128x128, BK=64) ----------------
template<int KD>
__device__ __forceinline__ void gemm_loop(const ushort_t* __restrict__ A,
                                          const ushort_t* __restrict__ Bt,
                                          ushort_t* al, ushort_t* bl,
                                          int bm, int bn, f32x4 acc[4][4])
{
    const int tid = threadIdx.x, w = tid >> 6, l = tid & 63;
    const int lm = l & 15, lh = l >> 4;
    const int wm = w >> 1, wn = w & 1;
    const int lr = l >> 3, lc = (l & 7) * 8;
    for (int k0 = 0; k0 < KD; k0 += 64) {
#pragma unroll
        for (int i = 0; i < 4; ++i) {
            const int c = w * 4 + i;
            const ushort_t* ga = A + (size_t)(bm + c * 8 + lr) * KD + k0 + lc;
            const ushort_t* gb = Bt + (size_t)(bn + c * 8 + lr) * KD + k0 + lc;
            __builtin_amdgcn_global_load_lds((gas_t)ga, (las_t)(al + c * 512), 16, 0, 0);
            __builtin_amdgcn_global_load_lds((gas_t)gb, (las_t)(bl + c * 512), 16, 0, 0);
        }
        __syncthreads();
#pragma unroll
        for (int kt = 0; kt < 2; ++kt) {
            short8 af[4], bfr[4];
            const int ko = kt * 32 + lh * 8;
#pragma unroll
            for (int m = 0; m < 4; ++m)
                af[m] = *(const short8*)(al + (wm * 64 + m * 16 + lm) * 64 + ko);
#pragma unroll
            for (int n = 0; n < 4; ++n)
                bfr[n] = *(const short8*)(bl + (wn * 64 + n * 16 + lm) * 64 + ko);
#pragma unroll
            for (int m = 0; m < 4; ++m)
#pragma unroll
                for (int n = 0; n < 4; ++n)
                    acc[m][n] = mfma16(af[m], bfr[n], acc[m][n]);
        }
        __syncthreads();
    }
}

// ---------------- xw GEMM: [4096][256] @ [256][1536] + bias2 -> packed bf16 ----------
__global__ void __launch_bounds__(256, 2)
k_gemm_xw(const ushort_t* __restrict__ xbf, const ushort_t* __restrict__ wih_bt,
          const float* __restrict__ bias2, ushort_t* __restrict__ xw3)
{
    __shared__ __align__(16) ushort_t al[128 * 64], bl[128 * 64];
    f32x4 acc[4][4] = {};
    const int bm = blockIdx.y * 128, bn = blockIdx.x * 128;
    gemm_loop<256>(xbf, wih_bt, al, bl, bm, bn, acc);
    const int tid = threadIdx.x, w = tid >> 6, l = tid & 63;
    const int lm = l & 15, lh = l >> 4, wm = w >> 1, wn = w & 1;
#pragma unroll
    for (int m = 0; m < 4; ++m)
#pragma unroll
        for (int rr = 0; rr < 4; ++rr) {
            const int row = bm + wm * 64 + m * 16 + lh * 4 + rr;
#pragma unroll
            for (int n = 0; n < 4; ++n) {
                const int col = bn + wn * 64 + n * 16 + lm;
                xw3[(size_t)row * 1536 + xw3_remap(col)] = f2bf(acc[m][n][rr] + bias2[col]);
            }
        }
}

// ---------------- GRU scan core (8 waves, three-tier, pipelined stream) ----------
// wave w owns hidden cols [w*32, w*32+32) as pairs (2lm, 2lm+1), all 3 gates.
// Stream tier (q28..47) runs as a 2-chain x 4-frag pipeline; b0/b1 for step t
// are issued during step t-1's gates phase (weights are h-independent).
#define AF(kt) (*(const short8*)(hb + lm * 512 + (((kt) * 64 + lh * 16) ^ ((lm & 7) << 4))))

template<bool IS_BASE>
__device__ __forceinline__ void scan_run(int dir, int sg, int tid,
    const ushort_t* __restrict__ xw3, const ushort_t* __restrict__ whhp,
    const float* __restrict__ bhh, ushort_t* __restrict__ wl,
    ushort_t (*hl)[4096], const int* idr,
    ushort_t* __restrict__ nx, float* __restrict__ base_v)
{
    const int w = tid >> 6, l = tid & 63;
    const int lm = l & 15, lh = l >> 4;
    const int nsteps = IS_BASE ? NNODE : PLEN;
    const ushort_t* wp = whhp + ((size_t)(dir * 8 + w) * 48) * 512 + l * 8;

    // REG tier: q0..11 (kt0, kt1), pinned against remat/sink
    short8 Breg[12];
#pragma unroll
    for (int q = 0; q < 12; ++q) {
        short8 v = *(const short8*)(wp + q * 512);
        asm volatile("" : "+v"(v));
        Breg[q] = v;
    }
    // LDS tier: q12..27 -> wl
#pragma unroll
    for (int q = 12; q < 28; ++q)
        __builtin_amdgcn_global_load_lds((gas_t)(wp + q * 512),
            (las_t)(wl + ((q - 12) * 8 + w) * 512), 16, 0, 0);

    const float bn0 = bhh[512 + w * 32 + lm * 2];
    const float bn1 = bhh[512 + w * 32 + lm * 2 + 1];

    __syncthreads();
    for (int i = tid; i < 4096; i += 512) hl[0][i] = 0;
    // stream pipeline prologue: b0 -> stA, b1 -> stB
    short8 stA[4], stB[4];
#pragma unroll
    for (int j = 0; j < 4; ++j) stA[j] = *(const short8*)(wp + (28 + j) * 512);
#pragma unroll
    for (int j = 0; j < 4; ++j) stB[j] = *(const short8*)(wp + (32 + j) * 512);
    __syncthreads();

    int cur = 0;
    for (int step = 0; step < nsteps; ++step) {
        const int t = dir ? (nsteps - 1 - step) : step;
        // xw gather: 12B per (lane, ri) (consumed at gates; latency fully hidden)
        uint3 gv[4];
#pragma unroll
        for (int ri = 0; ri < 4; ++ri) {
            const int sq = lh * 4 + ri;
            const int row = IS_BASE ? ((sq < 8) ? ((sq << 9) + t) : 4096)
                                    : idr[(sq << 6) + t];
            gv[ri] = *(const uint3*)((const char*)xw3 +
                (size_t)row * 3072 + dir * 1536 + w * 192 + lm * 12);
        }

        f32x4 acc[3][2] = {};
        const char* hb = (const char*)hl[cur];
        const short8 af4 = AF(4);
        const short8 af5 = AF(5);
        // consume b0 (q28..31: kt4g2, kt5g0); reissue A <- b2 (q36..39)
        acc[2][0] = mfma16(af4, stA[0], acc[2][0]);
        acc[2][1] = mfma16(af4, stA[1], acc[2][1]);
        acc[0][0] = mfma16(af5, stA[2], acc[0][0]);
        acc[0][1] = mfma16(af5, stA[3], acc[0][1]);
#pragma unroll
        for (int j = 0; j < 4; ++j) stA[j] = *(const short8*)(wp + (36 + j) * 512);
        __builtin_amdgcn_sched_barrier(0);
        // consume b1 (q32..35: kt5 g1,g2); reissue B <- b3 (q40..43)
        acc[1][0] = mfma16(af5, stB[0], acc[1][0]);
        acc[1][1] = mfma16(af5, stB[1], acc[1][1]);
        acc[2][0] = mfma16(af5, stB[2], acc[2][0]);
        acc[2][1] = mfma16(af5, stB[3], acc[2][1]);
#pragma unroll
        for (int j = 0; j < 4; ++j) stB[j] = *(const short8*)(wp + (40 + j) * 512);
        __builtin_amdgcn_sched_barrier(0);
        // resident tiers (hide b2/b3 latency): REG kt0,kt1 + LDS kt2,kt3,kt4g0/g1
        {
            const short8 af0 = AF(0);
#pragma unroll
            for (int j = 0; j < 6; ++j)
                acc[j >> 1][j & 1] = mfma16(af0, Breg[j], acc[j >> 1][j & 1]);
            const short8 af1 = AF(1);
#pragma unroll
            for (int j = 0; j < 6; ++j)
                acc[j >> 1][j & 1] = mfma16(af1, Breg[6 + j], acc[j >> 1][j & 1]);
            const short8 af2 = AF(2);
#pragma unroll
            for (int j = 0; j < 6; ++j)
                acc[j >> 1][j & 1] = mfma16(af2,
                    *(const short8*)(wl + (j * 8 + w) * 512 + l * 8), acc[j >> 1][j & 1]);
            const short8 af3 = AF(3);
#pragma unroll
            for (int j = 0; j < 6; ++j)
                acc[j >> 1][j & 1] = mfma16(af3,
                    *(const short8*)(wl + ((6 + j) * 8 + w) * 512 + l * 8), acc[j >> 1][j & 1]);
#pragma unroll
            for (int j = 0; j < 4; ++j)
                acc[j >> 1][j & 1] = mfma16(af4,
                    *(const short8*)(wl + ((12 + j) * 8 + w) * 512 + l * 8), acc[j >> 1][j & 1]);
        }
        __builtin_amdgcn_sched_barrier(0);
        const short8 af6 = AF(6);
        // consume b2 (q36..39: kt6 g0,g1); reissue A <- b4 (q44..47)
        acc[0][0] = mfma16(af6, stA[0], acc[0][0]);
        acc[0][1] = mfma16(af6, stA[1], acc[0][1]);
        acc[1][0] = mfma16(af6, stA[2], acc[1][0]);
        acc[1][1] = mfma16(af6, stA[3], acc[1][1]);
#pragma unroll
        for (int j = 0; j < 4; ++j) stA[j] = *(const short8*)(wp + (44 + j) * 512);
        __builtin_amdgcn_sched_barrier(0);
        const short8 af7 = AF(7);
        // consume b3 (q40..43: kt6g2, kt7g0); reissue B <- b1' (next step)
        acc[2][0] = mfma16(af6, stB[0], acc[2][0]);
        acc[2][1] = mfma16(af6, stB[1], acc[2][1]);
        acc[0][0] = mfma16(af7, stB[2], acc[0][0]);
        acc[0][1] = mfma16(af7, stB[3], acc[0][1]);
#pragma unroll
        for (int j = 0; j < 4; ++j) stB[j] = *(const short8*)(wp + (32 + j) * 512);
        __builtin_amdgcn_sched_barrier(0);
        // consume b4 (q44..47: kt7 g1,g2); reissue A <- b0' (next step)
        acc[1][0] = mfma16(af7, stA[0], acc[1][0]);
        acc[1][1] = mfma16(af7, stA[1], acc[1][1]);
        acc[2][0] = mfma16(af7, stA[2], acc[2][0]);
        acc[2][1] = mfma16(af7, stA[3], acc[2][1]);
#pragma unroll
        for (int j = 0; j < 4; ++j) stA[j] = *(const short8*)(wp + (28 + j) * 512);
        __builtin_amdgcn_sched_barrier(0);

        // gates + h update (VALU phase hides b0'/b1' latency)
        ushort_t* hn_ = hl[cur ^ 1];
#pragma unroll
        for (int ri = 0; ri < 4; ++ri) {
            const int sq = lh * 4 + ri;
            const unsigned hv = *(const unsigned*)(hb + sq * 512 +
                ((w * 64 + lm * 4) ^ ((sq & 7) << 4)));
            unsigned hpack = 0;
            float hs0 = 0.f, hs1 = 0.f;
#pragma unroll
            for (int n = 0; n < 2; ++n) {
                const float xr = bf2f((ushort_t)(n ? (gv[ri].x >> 16) : (gv[ri].x & 0xffffu)));
                const float xz = bf2f((ushort_t)(n ? (gv[ri].y >> 16) : (gv[ri].y & 0xffffu)));
                const float xn = bf2f((ushort_t)(n ? (gv[ri].z >> 16) : (gv[ri].z & 0xffffu)));
                const float hov = bf2f((ushort_t)(n ? (hv >> 16) : (hv & 0xffffu)));
                const float rr = sigm(acc[0][n][ri] + xr);
                const float zz = sigm(acc[1][n][ri] + xz);
                const float nn = tanh_(xn + rr * (acc[2][n][ri] + (n ? bn1 : bn0)));
                const float h = (1.f - zz) * nn + zz * hov;
                if (n) hs1 = h; else hs0 = h;
                hpack |= ((unsigned)f2bf(h)) << (n * 16);
            }
            *(unsigned*)((char*)hn_ + sq * 512 + ((w * 64 + lm * 4) ^ ((sq & 7) << 4))) = hpack;
            if (IS_BASE) {
                if (sq < 8)
                    *(float2*)(base_v + ((size_t)(sq * NNODE + t)) * 512 +
                               dir * 256 + w * 32 + lm * 2) = make_float2(hs0, hs1);
            } else {
                *(unsigned*)((char*)nx + (((size_t)((sg * 16 + sq) * PLEN + t)) * 512 +
                    dir * 256 + w * 32 + lm * 2) * 2) = hpack;
            }
        }
        __syncthreads();
        cur ^= 1;
    }
}
#undef AF

// ---------------- fused: blocks 0,1 = base GRU; 2..129 = path scan + rank GEMM ----
__global__ void __launch_bounds__(512)
k_scan(const int* __restrict__ paths, const ushort_t* __restrict__ xw3,
       const ushort_t* __restrict__ whhp,
       const float* __restrict__ bf_hh, const float* __restrict__ bb_hh,
       const ushort_t* __restrict__ wr_bt, const float* __restrict__ b_rank,
       const float* __restrict__ rank_l,
       ushort_t* __restrict__ nx, float* __restrict__ base_v,
       unsigned* __restrict__ keys)
{
    __shared__ __align__(16) ushort_t wl[65536];    // 128KB: weights (scan) / al,bl (rank)
    __shared__ __align__(16) ushort_t hl[2][4096];  // 16KB h double-buffer
    __shared__ int idr[1024];                       // 4KB -> 148.5KB (1 block/CU)
    const int tid = threadIdx.x;
    const int w = tid >> 6, l = tid & 63;
    const int lm = l & 15, lh = l >> 4;

    if (blockIdx.x < 2) {
        scan_run<true>((int)blockIdx.x, 0, tid, xw3, whhp,
                       blockIdx.x ? bb_hh : bf_hh, wl, hl, nullptr, nx, base_v);
        return;
    }
    const int sg = (int)blockIdx.x - 2;
    for (int i = tid; i < 1024; i += 512) {
        const int s = sg * 16 + (i >> 6), t = i & 63;
        const int id = paths[(s << 6) + t];
        idr[i] = (id < NNODE) ? (((s >> 8) << 9) + id) : 4096;
    }
    scan_run<false>(0, sg, tid, xw3, whhp, bf_hh, wl, hl, idr, nx, base_v);
    scan_run<false>(1, sg, tid, xw3, whhp, bb_hh, wl, hl, idr, nx, base_v);

    // ---- rank phase: own 1024 nx rows @ wr^T, 32 jobs of 128x128 tiles, K=512 ----
    __threadfence_block();
    __syncthreads();
    ushort_t* al = wl;                // weights dead; reuse as GEMM staging
    ushort_t* bl = wl + 8192;
    const int wm = w >> 2, wn = w & 3;   // wave tile 64x32
#pragma unroll 1
    for (int job = 0; job < 32; ++job) {
        const int mt = job >> 2, ntile = job & 3;
        const size_t ar0 = (size_t)sg * 1024 + mt * 128;
        const int n0 = ntile * 128;
        f32x4 racc[4][2] = {};
        for (int k0 = 0; k0 < 512; k0 += 64) {
#pragma unroll
            for (int i = 0; i < 2; ++i) {
                const int c = w * 128 + i * 64 + l;
                const int row = c >> 3, j = c & 7;
                const int jp = j ^ (row & 7);   // pre-swizzled source (both-sides rule)
                __builtin_amdgcn_global_load_lds(
                    (gas_t)(nx + (ar0 + row) * 512 + k0 + jp * 8),
                    (las_t)(al + c * 8), 16, 0, 0);
                __builtin_amdgcn_global_load_lds(
                    (gas_t)(wr_bt + (size_t)(n0 + row) * 512 + k0 + jp * 8),
                    (las_t)(bl + c * 8), 16, 0, 0);
            }
            __syncthreads();
#pragma unroll
            for (int kt = 0; kt < 2; ++kt) {
                short8 av[4], bv[2];
#pragma unroll
                for (int m = 0; m < 4; ++m) {
                    const int r = wm * 64 + m * 16 + lm;
                    av[m] = *(const short8*)((const char*)al + r * 128 +
                            ((kt * 64 + lh * 16) ^ ((r & 7) << 4)));
                }
#pragma unroll
                for (int n = 0; n < 2; ++n) {
                    const int r = wn * 32 + n * 16 + lm;
                    bv[n] = *(const short8*)((const char*)bl + r * 128 +
                            ((kt * 64 + lh * 16) ^ ((r & 7) << 4)));
                }
#pragma unroll
                for (int m = 0; m < 4; ++m)
#pragma unroll
                    for (int n = 0; n < 2; ++n)
                        racc[m][n] = mfma16(av[m], bv[n], racc[m][n]);
            }
            __syncthreads();
        }
#pragma unroll
        for (int m = 0; m < 4; ++m)
#pragma unroll
            for (int rr = 0; rr < 4; ++rr) {
                const size_t grow = ar0 + wm * 64 + m * 16 + lh * 4 + rr;
                const int id = paths[grow];
                const float rv = __builtin_amdgcn_rcpf((float)(((grow >> 6) & 255) + 1));
                unsigned* kp = keys + (((grow >> 14) * 513 + id) << 9);
#pragma unroll
                for (int n = 0; n < 2; ++n) {
                    const int col = n0 + wn * 32 + n * 16 + lm;
                    const float v = racc[m][n][rr] + b_rank[col] + rank_l[col] * rv;
                    if (id < NNODE) {
                        const unsigned key = fkey(v);
                        if (key > kp[col]) atomicMax(kp + col, key);
                    }
                }
            }
    }
}

// ---------------- merge: v = has ? vmax : transit(x);  all_v = base_v + v ----------------
__global__ void k_merge(const unsigned* __restrict__ keys, const float* __restrict__ base_v,
                        const float* __restrict__ x, const float* __restrict__ w_transit,
                        const float* __restrict__ b_transit, float* __restrict__ out0)
{
    const int blk = blockIdx.x;
    const int b = blk >> 9, n = blk & 511;
    const int tid = threadIdx.x;
#pragma unroll
    for (int h = 0; h < 2; ++h) {
        const int o = tid + h * 256;
        const unsigned k = keys[((size_t)(b * 513 + n)) * 512 + o];
        float v;
        if (k) {
            v = fdec(k);
        } else {
            float a = b_transit[o];
            const float* wt = w_transit + o * HH;
            const float* xr = x + ((size_t)(b * NNODE + n)) * HH;
            for (int i = 0; i < HH; ++i) a += xr[i] * wt[i];
            v = a;
        }
        const size_t oi = ((size_t)(b * NNODE + n)) * 512 + o;
        out0[oi] = base_v[oi] + v;
    }
}

// ---------------- last_state: rowmax over nodes, then @ w_h.T + b_h ----------------
__global__ void k_last(const float* __restrict__ out0, const float* __restrict__ w_h,
                       const float* __restrict__ b_h, float* __restrict__ out1)
{
    __shared__ float m[512];
    const int b = blockIdx.x, tid = threadIdx.x;
#pragma unroll
    for (int h = 0; h < 2; ++h) {
        const int o = tid + h * 256;
        float mm = -3.4e38f;
        for (int n = 0; n < NNODE; ++n)
            mm = fmaxf(mm, out0[((size_t)(b * NNODE + n)) * 512 + o]);
        m[o] = mm;
    }
    __syncthreads();
    float a = b_h[tid];
    const float* wr = w_h + tid * 512;
    for (int j = 0; j < 512; ++j) a += m[j] * wr[j];
    out1[b * HH + tid] = a;
}

extern "C" void kernel_launch(void* const* d_in, const int* in_sizes, int n_in,
                              void* d_out, int out_size, void* d_ws, size_t ws_size,
                              hipStream_t stream)
{
    (void)in_sizes; (void)n_in; (void)out_size; (void)ws_size;
    const int* nodes = (const int*)d_in[0];
    const int* paths = (const int*)d_in[1];
    const float* emb = (const float*)d_in[2];
    const float* wf_ih = (const float*)d_in[3];
    const float* wf_hh = (const float*)d_in[4];
    const float* bf_ih = (const float*)d_in[5];
    const float* bf_hh = (const float*)d_in[6];
    const float* wb_ih = (const float*)d_in[7];
    const float* wb_hh = (const float*)d_in[8];
    const float* bb_ih = (const float*)d_in[9];
    const float* bb_hh = (const float*)d_in[10];
    const float* w_transit = (const float*)d_in[11];
    const float* b_transit = (const float*)d_in[12];
    const float* w_rank = (const float*)d_in[13];
    const float* b_rank = (const float*)d_in[14];
    const float* w_h = (const float*)d_in[15];
    const float* b_h = (const float*)d_in[16];

    char* ws = (char*)d_ws;
    float* x = (float*)(ws);
    ushort_t* xbf = (ushort_t*)(ws + 4194304);
    ushort_t* xw3 = (ushort_t*)(ws + 6291456);
    ushort_t* whhp = (ushort_t*)(ws + 18877440);
    ushort_t* wih_bt = (ushort_t*)(ws + 19663872);
    ushort_t* wr_bt = (ushort_t*)(ws + 20450304);
    float* rank_l = (float*)(ws + 20974592);
    float* bias2 = (float*)(ws + 20976640);
    unsigned* keys = (unsigned*)(ws + 20982784);
    float* base_v = (float*)(ws + 29387776);
    ushort_t* nx = (ushort_t*)(ws + 37776384);

    float* out0 = (float*)d_out;
    float* out1 = out0 + 2097152;

    hipMemsetAsync(keys, 0, 8404992, stream);
    k_embed<<<4096, 256, 0, stream>>>(nodes, emb, x, xbf);
    k_pack<<<4104, 256, 0, stream>>>(wf_ih, wf_hh, bf_ih, bf_hh, wb_ih, wb_hh,
                                     bb_ih, bb_hh, w_rank,
                                     whhp, wih_bt, wr_bt, rank_l, bias2, xw3);
    k_gemm_xw<<<dim3(12, 32), 256, 0, stream>>>(xbf, wih_bt, bias2, xw3);
    k_scan<<<130, 512, 0, stream>>>(paths, xw3, whhp, bf_hh, bb_hh, wr_bt,
                                    b_rank, rank_l, nx, base_v, keys);
    k_merge<<<4096, 256, 0, stream>>>(keys, base_v, x, w_transit, b_transit, out0);
    k_last<<<8, 256, 0, stream>>>(out0, w_h, b_h, out1);
}

// Round 12
// 1693.403 us; speedup vs baseline: 1.5345x; 1.0956x over previous
//
#include <hip/hip_runtime.h>

// PathEncoder: B=8, N_NODE=512, N_TOK=8, N_PATHS=256, PATH_LEN=64, VOCAB=50000, H=256
// Round 12: r11 + XCD-locality remap for path blocks. Counter evidence (r11):
// FETCH_SIZE 398MB == exactly the path xw3 gather volume (128blk x 2dir x 64st
// x 16rows x 1536B = 402MB) -> gathers are HBM misses (nx/rank streaming evicts
// the 12.6MB xw3 table). Fix: all 16 path blocks of batch b -> XCD b (blockIdx
// round-robins XCDs), so each XCD's gather set = 1 batch slice = 1.57MB <= 4MB
// L2. sg remap: x=g&7, j=(g>>3)-(x<2), sg=x*16+j (bijective for g in [2,129]).
//
// ws layout (bytes): identical to round 9/11.
//   x       @ 0          4,194,304   [4096][256] f32
//   xbf     @ 4194304    2,097,152   [4096][256] bf16
//   xw3     @ 6291456   12,585,984   [4097]x1536 bf16 packed (r9 layout)
//   whhp    @ 18877440     786,432   packed whh bf16 B-frags, chunk (dir*8+w)*48+q
//   wih_bt  @ 19663872     786,432   [1536][256] bf16 concat(wf_ih, wb_ih)
//   wr_bt   @ 20450304     524,288   [512][512] bf16 w_rank[:, :512]
//   rank_l  @ 20974592       2,048   [512] f32
//   bias2   @ 20976640       6,144   [1536] f32
//   keys    @ 20982784   8,404,992   [8][513][512] u32 scatter-max
//   base_v  @ 29387776   8,388,608   [8][512][512] f32
//   nx      @ 37776384 134,217,728   [131072][512] bf16

#define HH 256
#define NNODE 512
#define PLEN 64

typedef __attribute__((ext_vector_type(8))) short short8;
typedef __attribute__((ext_vector_type(4))) float f32x4;
typedef unsigned short ushort_t;
typedef __attribute__((address_space(1))) const void* gas_t;
typedef __attribute__((address_space(3))) void* las_t;

__device__ __forceinline__ f32x4 mfma16(short8 a, short8 b, f32x4 c) {
    return __builtin_amdgcn_mfma_f32_16x16x32_bf16(a, b, c, 0, 0, 0);
}
__device__ __forceinline__ ushort_t f2bf(float f) {
    unsigned u = __float_as_uint(f);
    u += 0x7fffu + ((u >> 16) & 1u);
    return (ushort_t)(u >> 16);
}
__device__ __forceinline__ float bf2f(ushort_t s) {
    return __uint_as_float(((unsigned)s) << 16);
}
__device__ __forceinline__ float sigm(float x) {
    return __builtin_amdgcn_rcpf(1.f + __expf(-x));
}
__device__ __forceinline__ float tanh_(float x) {
    return 1.f - 2.f * __builtin_amdgcn_rcpf(__expf(2.f * x) + 1.f);
}
__device__ __forceinline__ unsigned fkey(float f) {
    unsigned u = __float_as_uint(f);
    return (u & 0x80000000u) ? ~u : (u | 0x80000000u);
}
__device__ __forceinline__ float fdec(unsigned k) {
    unsigned u = (k & 0x80000000u) ? (k ^ 0x80000000u) : ~k;
    return __uint_as_float(u);
}

// xw3 remap (r9): col c in [0,1536) -> packed element offset within a row.
__device__ __forceinline__ int xw3_remap(int c) {
    const int dir = c >= 768;
    const int cd = c - dir * 768;
    const int g = cd >> 8, cc = cd & 255;
    const int w2 = cc >> 5, within = cc & 31;
    return dir * 768 + w2 * 96 + (within >> 1) * 6 + g * 2 + (within & 1);
}

// ---------------- embedding token max-pool ----------------
__global__ void k_embed(const int* __restrict__ nodes, const float* __restrict__ emb,
                        float* __restrict__ x, ushort_t* __restrict__ xbf)
{
    const int bn = blockIdx.x, h = threadIdx.x;
    const int* nd = nodes + bn * 8;
    float m = -3.4e38f;
#pragma unroll
    for (int k = 0; k < 8; ++k)
        m = fmaxf(m, emb[(size_t)nd[k] * HH + h]);
    x[(size_t)bn * HH + h] = m;
    xbf[(size_t)bn * HH + h] = f2bf(m);
}

// ---------------- pack weights (identical to r9) ----------------
__global__ void k_pack(const float* __restrict__ wf_ih, const float* __restrict__ wf_hh,
                       const float* __restrict__ bf_ih, const float* __restrict__ bf_hh,
                       const float* __restrict__ wb_ih, const float* __restrict__ wb_hh,
                       const float* __restrict__ bb_ih, const float* __restrict__ bb_hh,
                       const float* __restrict__ w_rank,
                       ushort_t* __restrict__ whhp, ushort_t* __restrict__ wih_bt,
                       ushort_t* __restrict__ wr_bt, float* __restrict__ rank_l,
                       float* __restrict__ bias2, ushort_t* __restrict__ xw3)
{
    int i = blockIdx.x * 256 + threadIdx.x;
    if (i < 393216) {
        const int e = i & 7, l = (i >> 3) & 63;
        const int c = i >> 9;
        const int q = c % 48;
        const int w2 = (c / 48) & 7;
        const int dir = c / 384;
        int kt, g;
        if (q < 12)      { kt = q / 6;            g = (q % 6) >> 1; }
        else if (q < 24) { kt = 2 + (q - 12) / 6; g = ((q - 12) % 6) >> 1; }
        else if (q < 28) { kt = 4;                g = (q - 24) >> 1; }
        else if (q < 30) { kt = 4;                g = 2; }
        else             { kt = 5 + (q - 30) / 6; g = ((q - 30) % 6) >> 1; }
        const int n = q & 1;
        const float* whh = dir ? wb_hh : wf_hh;
        whhp[i] = f2bf(whh[(g * 256 + w2 * 32 + 2 * (l & 15) + n) * 256 +
                           kt * 32 + (l >> 4) * 8 + e]);
        return;
    }
    i -= 393216;
    if (i < 393216) {   // wih_bt [1536][256]
        const int n = i >> 8, k = i & 255;
        const float* wih = (n < 768) ? wf_ih : wb_ih;
        wih_bt[i] = f2bf(wih[(n % 768) * 256 + k]);
        return;
    }
    i -= 393216;
    if (i < 262144) { wr_bt[i] = f2bf(w_rank[(i >> 9) * 513 + (i & 511)]); return; }
    i -= 262144;
    if (i < 512) { rank_l[i] = w_rank[i * 513 + 512]; return; }
    i -= 512;
    if (i < 1536) {
        const int c = i;
        const int dir = c >= 768;
        const int cd = c - dir * 768;
        const int g = cd >> 8;
        const float bi = dir ? bb_ih[cd] : bf_ih[cd];
        const float bh = (g < 2) ? (dir ? bb_hh[cd] : bf_hh[cd]) : 0.f;
        bias2[c] = bi + bh;
        xw3[(size_t)4096 * 1536 + xw3_remap(c)] = f2bf(bi + bh);  // padding row
    }
}

// ---------------- GEMM mainloop (256 thr, 128x128, BK=64) ----------------
template<int KD>
__device__ __forceinline__ void gemm_loop(const ushort_t* __restrict__ A,
                                          const ushort_t* __restrict__ Bt,
                                          ushort_t* al, ushort_t* bl,
                                          int bm, int bn, f32x4 acc[4][4])
{
    const int tid = threadIdx.x, w = tid >> 6, l = tid & 63;
    const int lm = l & 15, lh = l >> 4;
    const int wm = w >> 1, wn = w & 1;
    const int lr = l >> 3, lc = (l & 7) * 8;
    for (int k0 = 0; k0 < KD; k0 += 64) {
#pragma unroll
        for (int i = 0; i < 4; ++i) {
            const int c = w * 4 + i;
            const ushort_t* ga = A + (size_t)(bm + c * 8 + lr) * KD + k0 + lc;
            const ushort_t* gb = Bt + (size_t)(bn + c * 8 + lr) * KD + k0 + lc;
            __builtin_amdgcn_global_load_lds((gas_t)ga, (las_t)(al + c * 512), 16, 0, 0);
            __builtin_amdgcn_global_load_lds((gas_t)gb, (las_t)(bl + c * 512), 16, 0, 0);
        }
        __syncthreads();
#pragma unroll
        for (int kt = 0; kt < 2; ++kt) {
            short8 af[4], bfr[4];
            const int ko = kt * 32 + lh * 8;
#pragma unroll
            for (int m = 0; m < 4; ++m)
                af[m] = *(const short8*)(al + (wm * 64 + m * 16 + lm) * 64 + ko);
#pragma unroll
            for (int n = 0; n < 4; ++n)
                bfr[n] = *(const short8*)(bl + (wn * 64 + n * 16 + lm) * 64 + ko);
#pragma unroll
            for (int m = 0; m < 4; ++m)
#pragma unroll
                for (int n = 0; n < 4; ++n)
                    acc[m][n] = mfma16(af[m], bfr[n], acc[m][n]);
        }
        __syncthreads();
    }
}

// ---------------- xw GEMM: [4096][256] @ [256][1536] + bias2 -> packed bf16 ----------
__global__ void __launch_bounds__(256, 2)
k_gemm_xw(const ushort_t* __restrict__ xbf, const ushort_t* __restrict__ wih_bt,
          const float* __restrict__ bias2, ushort_t* __restrict__ xw3)
{
    __shared__ __align__(16) ushort_t al[128 * 64], bl[128 * 64];
    f32x4 acc[4][4] = {};
    const int bm = blockIdx.y * 128, bn = blockIdx.x * 128;
    gemm_loop<256>(xbf, wih_bt, al, bl, bm, bn, acc);
    const int tid = threadIdx.x, w = tid >> 6, l = tid & 63;
    const int lm = l & 15, lh = l >> 4, wm = w >> 1, wn = w & 1;
#pragma unroll
    for (int m = 0; m < 4; ++m)
#pragma unroll
        for (int rr = 0; rr < 4; ++rr) {
            const int row = bm + wm * 64 + m * 16 + lh * 4 + rr;
#pragma unroll
            for (int n = 0; n < 4; ++n) {
                const int col = bn + wn * 64 + n * 16 + lm;
                xw3[(size_t)row * 1536 + xw3_remap(col)] = f2bf(acc[m][n][rr] + bias2[col]);
            }
        }
}

// ---------------- GRU scan core (8 waves, three-tier, pipelined stream) ----------
#define AF(kt) (*(const short8*)(hb + lm * 512 + (((kt) * 64 + lh * 16) ^ ((lm & 7) << 4))))

template<bool IS_BASE>
__device__ __forceinline__ void scan_run(int dir, int sg, int tid,
    const ushort_t* __restrict__ xw3, const ushort_t* __restrict__ whhp,
    const float* __restrict__ bhh, ushort_t* __restrict__ wl,
    ushort_t (*hl)[4096], const int* idr,
    ushort_t* __restrict__ nx, float* __restrict__ base_v)
{
    const int w = tid >> 6, l = tid & 63;
    const int lm = l & 15, lh = l >> 4;
    const int nsteps = IS_BASE ? NNODE : PLEN;
    const ushort_t* wp = whhp + ((size_t)(dir * 8 + w) * 48) * 512 + l * 8;

    // REG tier: q0..11 (kt0, kt1), pinned against remat/sink
    short8 Breg[12];
#pragma unroll
    for (int q = 0; q < 12; ++q) {
        short8 v = *(const short8*)(wp + q * 512);
        asm volatile("" : "+v"(v));
        Breg[q] = v;
    }
    // LDS tier: q12..27 -> wl
#pragma unroll
    for (int q = 12; q < 28; ++q)
        __builtin_amdgcn_global_load_lds((gas_t)(wp + q * 512),
            (las_t)(wl + ((q - 12) * 8 + w) * 512), 16, 0, 0);

    const float bn0 = bhh[512 + w * 32 + lm * 2];
    const float bn1 = bhh[512 + w * 32 + lm * 2 + 1];

    __syncthreads();
    for (int i = tid; i < 4096; i += 512) hl[0][i] = 0;
    // stream pipeline prologue: b0 -> stA, b1 -> stB
    short8 stA[4], stB[4];
#pragma unroll
    for (int j = 0; j < 4; ++j) stA[j] = *(const short8*)(wp + (28 + j) * 512);
#pragma unroll
    for (int j = 0; j < 4; ++j) stB[j] = *(const short8*)(wp + (32 + j) * 512);
    __syncthreads();

    int cur = 0;
    for (int step = 0; step < nsteps; ++step) {
        const int t = dir ? (nsteps - 1 - step) : step;
        // xw gather: 12B per (lane, ri) (consumed at gates; latency hidden)
        uint3 gv[4];
#pragma unroll
        for (int ri = 0; ri < 4; ++ri) {
            const int sq = lh * 4 + ri;
            const int row = IS_BASE ? ((sq < 8) ? ((sq << 9) + t) : 4096)
                                    : idr[(sq << 6) + t];
            gv[ri] = *(const uint3*)((const char*)xw3 +
                (size_t)row * 3072 + dir * 1536 + w * 192 + lm * 12);
        }

        f32x4 acc[3][2] = {};
        const char* hb = (const char*)hl[cur];
        const short8 af4 = AF(4);
        const short8 af5 = AF(5);
        // consume b0 (q28..31: kt4g2, kt5g0); reissue A <- b2 (q36..39)
        acc[2][0] = mfma16(af4, stA[0], acc[2][0]);
        acc[2][1] = mfma16(af4, stA[1], acc[2][1]);
        acc[0][0] = mfma16(af5, stA[2], acc[0][0]);
        acc[0][1] = mfma16(af5, stA[3], acc[0][1]);
#pragma unroll
        for (int j = 0; j < 4; ++j) stA[j] = *(const short8*)(wp + (36 + j) * 512);
        __builtin_amdgcn_sched_barrier(0);
        // consume b1 (q32..35: kt5 g1,g2); reissue B <- b3 (q40..43)
        acc[1][0] = mfma16(af5, stB[0], acc[1][0]);
        acc[1][1] = mfma16(af5, stB[1], acc[1][1]);
        acc[2][0] = mfma16(af5, stB[2], acc[2][0]);
        acc[2][1] = mfma16(af5, stB[3], acc[2][1]);
#pragma unroll
        for (int j = 0; j < 4; ++j) stB[j] = *(const short8*)(wp + (40 + j) * 512);
        __builtin_amdgcn_sched_barrier(0);
        // resident tiers (hide b2/b3 latency): REG kt0,kt1 + LDS kt2,kt3,kt4g0/g1
        {
            const short8 af0 = AF(0);
#pragma unroll
            for (int j = 0; j < 6; ++j)
                acc[j >> 1][j & 1] = mfma16(af0, Breg[j], acc[j >> 1][j & 1]);
            const short8 af1 = AF(1);
#pragma unroll
            for (int j = 0; j < 6; ++j)
                acc[j >> 1][j & 1] = mfma16(af1, Breg[6 + j], acc[j >> 1][j & 1]);
            const short8 af2 = AF(2);
#pragma unroll
            for (int j = 0; j < 6; ++j)
                acc[j >> 1][j & 1] = mfma16(af2,
                    *(const short8*)(wl + (j * 8 + w) * 512 + l * 8), acc[j >> 1][j & 1]);
            const short8 af3 = AF(3);
#pragma unroll
            for (int j = 0; j < 6; ++j)
                acc[j >> 1][j & 1] = mfma16(af3,
                    *(const short8*)(wl + ((6 + j) * 8 + w) * 512 + l * 8), acc[j >> 1][j & 1]);
#pragma unroll
            for (int j = 0; j < 4; ++j)
                acc[j >> 1][j & 1] = mfma16(af4,
                    *(const short8*)(wl + ((12 + j) * 8 + w) * 512 + l * 8), acc[j >> 1][j & 1]);
        }
        __builtin_amdgcn_sched_barrier(0);
        const short8 af6 = AF(6);
        // consume b2 (q36..39: kt6 g0,g1); reissue A <- b4 (q44..47)
        acc[0][0] = mfma16(af6, stA[0], acc[0][0]);
        acc[0][1] = mfma16(af6, stA[1], acc[0][1]);
        acc[1][0] = mfma16(af6, stA[2], acc[1][0]);
        acc[1][1] = mfma16(af6, stA[3], acc[1][1]);
#pragma unroll
        for (int j = 0; j < 4; ++j) stA[j] = *(const short8*)(wp + (44 + j) * 512);
        __builtin_amdgcn_sched_barrier(0);
        const short8 af7 = AF(7);
        // consume b3 (q40..43: kt6g2, kt7g0); reissue B <- b1' (next step)
        acc[2][0] = mfma16(af6, stB[0], acc[2][0]);
        acc[2][1] = mfma16(af6, stB[1], acc[2][1]);
        acc[0][0] = mfma16(af7, stB[2], acc[0][0]);
        acc[0][1] = mfma16(af7, stB[3], acc[0][1]);
#pragma unroll
        for (int j = 0; j < 4; ++j) stB[j] = *(const short8*)(wp + (32 + j) * 512);
        __builtin_amdgcn_sched_barrier(0);
        // consume b4 (q44..47: kt7 g1,g2); reissue A <- b0' (next step)
        acc[1][0] = mfma16(af7, stA[0], acc[1][0]);
        acc[1][1] = mfma16(af7, stA[1], acc[1][1]);
        acc[2][0] = mfma16(af7, stA[2], acc[2][0]);
        acc[2][1] = mfma16(af7, stA[3], acc[2][1]);
#pragma unroll
        for (int j = 0; j < 4; ++j) stA[j] = *(const short8*)(wp + (28 + j) * 512);
        __builtin_amdgcn_sched_barrier(0);

        // gates + h update (VALU phase hides b0'/b1' latency)
        ushort_t* hn_ = hl[cur ^ 1];
#pragma unroll
        for (int ri = 0; ri < 4; ++ri) {
            const int sq = lh * 4 + ri;
            const unsigned hv = *(const unsigned*)(hb + sq * 512 +
                ((w * 64 + lm * 4) ^ ((sq & 7) << 4)));
            unsigned hpack = 0;
            float hs0 = 0.f, hs1 = 0.f;
#pragma unroll
            for (int n = 0; n < 2; ++n) {
                const float xr = bf2f((ushort_t)(n ? (gv[ri].x >> 16) : (gv[ri].x & 0xffffu)));
                const float xz = bf2f((ushort_t)(n ? (gv[ri].y >> 16) : (gv[ri].y & 0xffffu)));
                const float xn = bf2f((ushort_t)(n ? (gv[ri].z >> 16) : (gv[ri].z & 0xffffu)));
                const float hov = bf2f((ushort_t)(n ? (hv >> 16) : (hv & 0xffffu)));
                const float rr = sigm(acc[0][n][ri] + xr);
                const float zz = sigm(acc[1][n][ri] + xz);
                const float nn = tanh_(xn + rr * (acc[2][n][ri] + (n ? bn1 : bn0)));
                const float h = (1.f - zz) * nn + zz * hov;
                if (n) hs1 = h; else hs0 = h;
                hpack |= ((unsigned)f2bf(h)) << (n * 16);
            }
            *(unsigned*)((char*)hn_ + sq * 512 + ((w * 64 + lm * 4) ^ ((sq & 7) << 4))) = hpack;
            if (IS_BASE) {
                if (sq < 8)
                    *(float2*)(base_v + ((size_t)(sq * NNODE + t)) * 512 +
                               dir * 256 + w * 32 + lm * 2) = make_float2(hs0, hs1);
            } else {
                *(unsigned*)((char*)nx + (((size_t)((sg * 16 + sq) * PLEN + t)) * 512 +
                    dir * 256 + w * 32 + lm * 2) * 2) = hpack;
            }
        }
        __syncthreads();
        cur ^= 1;
    }
}
#undef AF

// ---------------- fused: blocks 0,1 = base GRU; 2..129 = path scan + rank GEMM ----
__global__ void __launch_bounds__(512)
k_scan(const int* __restrict__ paths, const ushort_t* __restrict__ xw3,
       const ushort_t* __restrict__ whhp,
       const float* __restrict__ bf_hh, const float* __restrict__ bb_hh,
       const ushort_t* __restrict__ wr_bt, const float* __restrict__ b_rank,
       const float* __restrict__ rank_l,
       ushort_t* __restrict__ nx, float* __restrict__ base_v,
       unsigned* __restrict__ keys)
{
    __shared__ __align__(16) ushort_t wl[65536];    // 128KB: weights (scan) / al,bl (rank)
    __shared__ __align__(16) ushort_t hl[2][4096];  // 16KB h double-buffer
    __shared__ int idr[1024];                       // 4KB -> 148.5KB (1 block/CU)
    const int tid = threadIdx.x;
    const int w = tid >> 6, l = tid & 63;
    const int lm = l & 15, lh = l >> 4;

    if (blockIdx.x < 2) {
        scan_run<true>((int)blockIdx.x, 0, tid, xw3, whhp,
                       blockIdx.x ? bb_hh : bf_hh, wl, hl, nullptr, nx, base_v);
        return;
    }
    // XCD-locality remap: blockIdx g -> XCD g&7 (round-robin dispatch). Choose
    // sg so that batch(sg) == XCD: all 16 blocks of batch b gather from the
    // same 1.57MB xw3 slice, resident in XCD b's L2.
    const int g = (int)blockIdx.x;
    const int xcd = g & 7;
    const int sg = xcd * 16 + ((g >> 3) - (xcd < 2 ? 1 : 0));
    for (int i = tid; i < 1024; i += 512) {
        const int s = sg * 16 + (i >> 6), t = i & 63;
        const int id = paths[(s << 6) + t];
        idr[i] = (id < NNODE) ? (((s >> 8) << 9) + id) : 4096;
    }
    scan_run<false>(0, sg, tid, xw3, whhp, bf_hh, wl, hl, idr, nx, base_v);
    scan_run<false>(1, sg, tid, xw3, whhp, bb_hh, wl, hl, idr, nx, base_v);

    // ---- rank phase: own 1024 nx rows @ wr^T, 32 jobs of 128x128 tiles, K=512 ----
    __threadfence_block();
    __syncthreads();
    ushort_t* al = wl;                // weights dead; reuse as GEMM staging
    ushort_t* bl = wl + 8192;
    const int wm = w >> 2, wn = w & 3;   // wave tile 64x32
#pragma unroll 1
    for (int job = 0; job < 32; ++job) {
        const int mt = job >> 2, ntile = job & 3;
        const size_t ar0 = (size_t)sg * 1024 + mt * 128;
        const int n0 = ntile * 128;
        f32x4 racc[4][2] = {};
        for (int k0 = 0; k0 < 512; k0 += 64) {
#pragma unroll
            for (int i = 0; i < 2; ++i) {
                const int c = w * 128 + i * 64 + l;
                const int row = c >> 3, j = c & 7;
                const int jp = j ^ (row & 7);   // pre-swizzled source (both-sides rule)
                __builtin_amdgcn_global_load_lds(
                    (gas_t)(nx + (ar0 + row) * 512 + k0 + jp * 8),
                    (las_t)(al + c * 8), 16, 0, 0);
                __builtin_amdgcn_global_load_lds(
                    (gas_t)(wr_bt + (size_t)(n0 + row) * 512 + k0 + jp * 8),
                    (las_t)(bl + c * 8), 16, 0, 0);
            }
            __syncthreads();
#pragma unroll
            for (int kt = 0; kt < 2; ++kt) {
                short8 av[4], bv[2];
#pragma unroll
                for (int m = 0; m < 4; ++m) {
                    const int r = wm * 64 + m * 16 + lm;
                    av[m] = *(const short8*)((const char*)al + r * 128 +
                            ((kt * 64 + lh * 16) ^ ((r & 7) << 4)));
                }
#pragma unroll
                for (int n = 0; n < 2; ++n) {
                    const int r = wn * 32 + n * 16 + lm;
                    bv[n] = *(const short8*)((const char*)bl + r * 128 +
                            ((kt * 64 + lh * 16) ^ ((r & 7) << 4)));
                }
#pragma unroll
                for (int m = 0; m < 4; ++m)
#pragma unroll
                    for (int n = 0; n < 2; ++n)
                        racc[m][n] = mfma16(av[m], bv[n], racc[m][n]);
            }
            __syncthreads();
        }
#pragma unroll
        for (int m = 0; m < 4; ++m)
#pragma unroll
            for (int rr = 0; rr < 4; ++rr) {
                const size_t grow = ar0 + wm * 64 + m * 16 + lh * 4 + rr;
                const int id = paths[grow];
                const float rv = __builtin_amdgcn_rcpf((float)(((grow >> 6) & 255) + 1));
                unsigned* kp = keys + (((grow >> 14) * 513 + id) << 9);
#pragma unroll
                for (int n = 0; n < 2; ++n) {
                    const int col = n0 + wn * 32 + n * 16 + lm;
                    const float v = racc[m][n][rr] + b_rank[col] + rank_l[col] * rv;
                    if (id < NNODE) {
                        const unsigned key = fkey(v);
                        if (key > kp[col]) atomicMax(kp + col, key);
                    }
                }
            }
    }
}

// ---------------- merge: v = has ? vmax : transit(x);  all_v = base_v + v ----------------
__global__ void k_merge(const unsigned* __restrict__ keys, const float* __restrict__ base_v,
                        const float* __restrict__ x, const float* __restrict__ w_transit,
                        const float* __restrict__ b_transit, float* __restrict__ out0)
{
    const int blk = blockIdx.x;
    const int b = blk >> 9, n = blk & 511;
    const int tid = threadIdx.x;
#pragma unroll
    for (int h = 0; h < 2; ++h) {
        const int o = tid + h * 256;
        const unsigned k = keys[((size_t)(b * 513 + n)) * 512 + o];
        float v;
        if (k) {
            v = fdec(k);
        } else {
            float a = b_transit[o];
            const float* wt = w_transit + o * HH;
            const float* xr = x + ((size_t)(b * NNODE + n)) * HH;
            for (int i = 0; i < HH; ++i) a += xr[i] * wt[i];
            v = a;
        }
        const size_t oi = ((size_t)(b * NNODE + n)) * 512 + o;
        out0[oi] = base_v[oi] + v;
    }
}

// ---------------- last_state: rowmax over nodes, then @ w_h.T + b_h ----------------
__global__ void k_last(const float* __restrict__ out0, const float* __restrict__ w_h,
                       const float* __restrict__ b_h, float* __restrict__ out1)
{
    __shared__ float m[512];
    const int b = blockIdx.x, tid = threadIdx.x;
#pragma unroll
    for (int h = 0; h < 2; ++h) {
        const int o = tid + h * 256;
        float mm = -3.4e38f;
        for (int n = 0; n < NNODE; ++n)
            mm = fmaxf(mm, out0[((size_t)(b * NNODE + n)) * 512 + o]);
        m[o] = mm;
    }
    __syncthreads();
    float a = b_h[tid];
    const float* wr = w_h + tid * 512;
    for (int j = 0; j < 512; ++j) a += m[j] * wr[j];
    out1[b * HH + tid] = a;
}

extern "C" void kernel_launch(void* const* d_in, const int* in_sizes, int n_in,
                              void* d_out, int out_size, void* d_ws, size_t ws_size,
                              hipStream_t stream)
{
    (void)in_sizes; (void)n_in; (void)out_size; (void)ws_size;
    const int* nodes = (const int*)d_in[0];
    const int* paths = (const int*)d_in[1];
    const float* emb = (const float*)d_in[2];
    const float* wf_ih = (const float*)d_in[3];
    const float* wf_hh = (const float*)d_in[4];
    const float* bf_ih = (const float*)d_in[5];
    const float* bf_hh = (const float*)d_in[6];
    const float* wb_ih = (const float*)d_in[7];
    const float* wb_hh = (const float*)d_in[8];
    const float* bb_ih = (const float*)d_in[9];
    const float* bb_hh = (const float*)d_in[10];
    const float* w_transit = (const float*)d_in[11];
    const float* b_transit = (const float*)d_in[12];
    const float* w_rank = (const float*)d_in[13];
    const float* b_rank = (const float*)d_in[14];
    const float* w_h = (const float*)d_in[15];
    const float* b_h = (const float*)d_in[16];

    char* ws = (char*)d_ws;
    float* x = (float*)(ws);
    ushort_t* xbf = (ushort_t*)(ws + 4194304);
    ushort_t* xw3 = (ushort_t*)(ws + 6291456);
    ushort_t* whhp = (ushort_t*)(ws + 18877440);
    ushort_t* wih_bt = (ushort_t*)(ws + 19663872);
    ushort_t* wr_bt = (ushort_t*)(ws + 20450304);
    float* rank_l = (float*)(ws + 20974592);
    float* bias2 = (float*)(ws + 20976640);
    unsigned* keys = (unsigned*)(ws + 20982784);
    float* base_v = (float*)(ws + 29387776);
    ushort_t* nx = (ushort_t*)(ws + 37776384);

    float* out0 = (float*)d_out;
    float* out1 = out0 + 2097152;

    hipMemsetAsync(keys, 0, 8404992, stream);
    k_embed<<<4096, 256, 0, stream>>>(nodes, emb, x, xbf);
    k_pack<<<4104, 256, 0, stream>>>(wf_ih, wf_hh, bf_ih, bf_hh, wb_ih, wb_hh,
                                     bb_ih, bb_hh, w_rank,
                                     whhp, wih_bt, wr_bt, rank_l, bias2, xw3);
    k_gemm_xw<<<dim3(12, 32), 256, 0, stream>>>(xbf, wih_bt, bias2, xw3);
    k_scan<<<130, 512, 0, stream>>>(paths, xw3, whhp, bf_hh, bb_hh, wr_bt,
                                    b_rank, rank_l, nx, base_v, keys);
    k_merge<<<4096, 256, 0, stream>>>(keys, base_v, x, w_transit, b_transit, out0);
    k_last<<<8, 256, 0, stream>>>(out0, w_h, b_h, out1);
}